// Round 8
// baseline (178.876 us; speedup 1.0000x reference)
//
#include <hip/hip_runtime.h>
#include <stdint.h>
#include <math.h>

using bf16x8 = __attribute__((ext_vector_type(8))) short;
using bf16x4 = __attribute__((ext_vector_type(4))) short;
using f32x4  = __attribute__((ext_vector_type(4))) float;

#define DEV static __device__ __forceinline__

// NOTE (session ledger): v_cvt_pk_bf16_f32 inline asm => NaN on this stack
// (round 6 vs 7 bisection). BK=64 swizzled-glds GEMM => NaN (round 5 vs 6).
// Both are banned. Scalar f2bf pack + BK=32 m97 GEMM are the proven forms.

DEV float bf2f(short s) {
  union { unsigned u; float f; } v; v.u = ((unsigned)(unsigned short)s) << 16; return v.f;
}
DEV short f2bf(float f) {
  union { float ff; unsigned u; } v; v.ff = f;
  unsigned r = v.u + 0x7fffu + ((v.u >> 16) & 1u);
  return (short)(r >> 16);
}

DEV f32x4 mfma16x16x32(bf16x8 a, bf16x8 b, f32x4 c) {
  return __builtin_amdgcn_mfma_f32_16x16x32_bf16(a, b, c, 0, 0, 0);
}

DEV void glds16(const void* g, void* l) {
  __builtin_amdgcn_global_load_lds(
      (__attribute__((address_space(1))) void*)(uintptr_t)(g),
      (__attribute__((address_space(3))) void*)(l), 16, 0, 0);
}

#define B_   2
#define N_   2048
#define DIM_ 1024
#define H_   16
#define DH_  64
#define BH_  (B_ * H_)
#define BN_  (B_ * N_)

// ---------------------------------------------------------------------------
// 1) cos/sin table: cs[(n*32+j)*2] = cos(n * 10000^(-2j/64)), +1 = sin
// ---------------------------------------------------------------------------
__global__ void cs_kernel(float* __restrict__ cs) {
  int tid = blockIdx.x * blockDim.x + threadIdx.x;   // 65536 = 2048 * 32
  int n = tid >> 5, j = tid & 31;
  float inv = powf(10000.0f, -(float)(2 * j) / 64.0f);
  float ang = (float)n * inv;
  cs[2 * tid]     = cosf(ang);
  cs[2 * tid + 1] = sinf(ang);
}

// ---------------------------------------------------------------------------
// 2) fp32 -> bf16 elementwise (for x)
// ---------------------------------------------------------------------------
__global__ __launch_bounds__(256) void conv_kernel(const float* __restrict__ src,
                                                   short* __restrict__ dst) {
  int i = (blockIdx.x * 256 + threadIdx.x) * 8;
  float4 a = *(const float4*)(src + i);
  float4 b = *(const float4*)(src + i + 4);
  bf16x8 o;
  o[0] = f2bf(a.x); o[1] = f2bf(a.y); o[2] = f2bf(a.z); o[3] = f2bf(a.w);
  o[4] = f2bf(b.x); o[5] = f2bf(b.y); o[6] = f2bf(b.z); o[7] = f2bf(b.w);
  *(bf16x8*)(dst + i) = o;
}

// ---------------------------------------------------------------------------
// 3) transpose fp32 [R][C] -> bf16 [C][R]  (64x64 LDS tiles)
// ---------------------------------------------------------------------------
__global__ __launch_bounds__(256) void transw_kernel(const float* __restrict__ src,
                                                     short* __restrict__ dst,
                                                     int R, int C) {
  __shared__ unsigned short lds[64 * 65];
  const int t = threadIdx.x;
  const int cb = blockIdx.x * 64, rb = blockIdx.y * 64;
  #pragma unroll
  for (int pass = 0; pass < 4; ++pass) {
    int r  = pass * 16 + (t >> 4);
    int cc = (t & 15) * 4;
    float4 v = *(const float4*)(src + (size_t)(rb + r) * C + cb + cc);
    lds[(cc + 0) * 65 + r] = (unsigned short)f2bf(v.x);
    lds[(cc + 1) * 65 + r] = (unsigned short)f2bf(v.y);
    lds[(cc + 2) * 65 + r] = (unsigned short)f2bf(v.z);
    lds[(cc + 3) * 65 + r] = (unsigned short)f2bf(v.w);
  }
  __syncthreads();
  const int cl = t >> 2, chunk = t & 3;
  bf16x8 o0, o1;
  #pragma unroll
  for (int j = 0; j < 8; ++j) {
    o0[j] = (short)lds[cl * 65 + chunk * 16 + j];
    o1[j] = (short)lds[cl * 65 + chunk * 16 + 8 + j];
  }
  size_t off = (size_t)(cb + cl) * R + rb + chunk * 16;
  *(bf16x8*)(dst + off)     = o0;
  *(bf16x8*)(dst + off + 8) = o1;
}

// ---------------------------------------------------------------------------
// 4) GEMM: C[M][N] = A[M][K] (bf16, row-major) @ BT[N][K]^T (bf16)
//    Round-3-proven m97 form: 128x128 tile, BK=32, 4 waves, linear-source
//    global_load_lds. 1D grid + bijective XCD swizzle (nwg % 8 == 0).
// ---------------------------------------------------------------------------
template <bool OUTBF16>
__global__ __launch_bounds__(256) void gemm_bt_kernel(const short* __restrict__ A,
                                                      const short* __restrict__ BT,
                                                      void* __restrict__ Cout,
                                                      int M, int N, int K, int gx) {
  __shared__ short As[128 * 32];
  __shared__ short Bs[128 * 32];
  const int nwg = gridDim.x;
  const int bid = blockIdx.x;
  const int swz = (bid & 7) * (nwg >> 3) + (bid >> 3);  // bijective: nwg%8==0
  const int bx = swz % gx, by = swz / gx;
  const int t = threadIdx.x;
  const int lane = t & 63, w = t >> 6;
  const int c = lane & 15, g = lane >> 4;
  const int wm = w >> 1, wn = w & 1;
  const int mbase = by * 128, nbase = bx * 128;
  const short* Ab = A + (size_t)mbase * K;
  const short* Bb = BT + (size_t)nbase * K;
  const int sr  = t >> 2;        // staging row 0..63
  const int sc2 = (t & 3) * 8;   // staging col chunk (8 bf16 = 16 B)
  f32x4 acc[4][4] = {};
  for (int kb2 = 0; kb2 < K; kb2 += 32) {
    glds16(Ab + (size_t)sr * K + kb2 + sc2,        As + t * 8);
    glds16(Ab + (size_t)(sr + 64) * K + kb2 + sc2, As + 2048 + t * 8);
    glds16(Bb + (size_t)sr * K + kb2 + sc2,        Bs + t * 8);
    glds16(Bb + (size_t)(sr + 64) * K + kb2 + sc2, Bs + 2048 + t * 8);
    __syncthreads();
    bf16x8 af[4], bfr[4];
    #pragma unroll
    for (int mi = 0; mi < 4; ++mi)
      af[mi] = *(const bf16x8*)&As[(wm * 64 + mi * 16 + c) * 32 + g * 8];
    #pragma unroll
    for (int ni = 0; ni < 4; ++ni)
      bfr[ni] = *(const bf16x8*)&Bs[(wn * 64 + ni * 16 + c) * 32 + g * 8];
    #pragma unroll
    for (int mi = 0; mi < 4; ++mi)
      #pragma unroll
      for (int ni = 0; ni < 4; ++ni)
        acc[mi][ni] = mfma16x16x32(af[mi], bfr[ni], acc[mi][ni]);
    __syncthreads();
  }
  #pragma unroll
  for (int mi = 0; mi < 4; ++mi) {
    const int row = mbase + wm * 64 + mi * 16 + g * 4;
    #pragma unroll
    for (int ni = 0; ni < 4; ++ni) {
      const int col = nbase + wn * 64 + ni * 16 + c;
      #pragma unroll
      for (int r = 0; r < 4; ++r) {
        if constexpr (OUTBF16)
          ((short*)Cout)[(size_t)(row + r) * N + col] = f2bf(acc[mi][ni][r]);
        else
          ((float*)Cout)[(size_t)(row + r) * N + col] = acc[mi][ni][r];
      }
    }
  }
}

// ---------------------------------------------------------------------------
// 5) RoPE on q,k: qkv bf16 [4096][3072] cols 0..2047 -> qb/kb [BH][N][64] bf16
//    q additionally scaled by 0.125 (EXACT pow2, folds softmax scale)
// ---------------------------------------------------------------------------
__global__ __launch_bounds__(256) void ropeqk_kernel(const short* __restrict__ qkv,
                                                     const float* __restrict__ cs,
                                                     short* __restrict__ qb,
                                                     short* __restrict__ kb) {
  int tid = blockIdx.x * 256 + threadIdx.x;  // 2097152 threads, 4 elems each
  int e   = tid * 4;
  int bn  = e >> 11;
  int col = e & 2047;
  int i3  = col >> 10;
  int h   = (col >> 6) & 15;
  int d   = col & 63;
  int n   = bn & (N_ - 1);
  int b   = bn >> 11;
  bf16x4 v = *(const bf16x4*)(qkv + (size_t)bn * 3072 + col);
  float4 t4 = *(const float4*)(cs + ((size_t)n * 32 + (d >> 1)) * 2); // c0,s0,c1,s1
  float x0 = bf2f(v[0]), x1 = bf2f(v[1]), x2 = bf2f(v[2]), x3 = bf2f(v[3]);
  float r0 = x0 * t4.x - x1 * t4.y;
  float r1 = x0 * t4.y + x1 * t4.x;
  float r2 = x2 * t4.z - x3 * t4.w;
  float r3 = x2 * t4.w + x3 * t4.z;
  float sc = (i3 == 0) ? 0.125f : 1.0f;
  bf16x4 ov;
  ov[0] = f2bf(r0 * sc); ov[1] = f2bf(r1 * sc);
  ov[2] = f2bf(r2 * sc); ov[3] = f2bf(r3 * sc);
  short* dst = (i3 == 0) ? qb : kb;
  *(bf16x4*)(dst + (((size_t)(b * H_ + h) * N_ + n) * DH_ + d)) = ov;
}

// ---------------------------------------------------------------------------
// 6) V transpose: qkv cols 2048..3071 -> vT [BH][64][N] bf16
// ---------------------------------------------------------------------------
__global__ __launch_bounds__(256) void transv_kernel(const short* __restrict__ qkv,
                                                     short* __restrict__ vT) {
  __shared__ unsigned short lds[64 * 65];
  const int t = threadIdx.x;
  const int ntile = blockIdx.x;  // 0..31
  const int bh = blockIdx.y;     // 0..31
  const int b = bh >> 4, h = bh & 15;
  #pragma unroll
  for (int pass = 0; pass < 2; ++pass) {
    int rloc = pass * 32 + (t >> 3);
    int dc = t & 7;
    const short* src = qkv + (size_t)(b * N_ + ntile * 64 + rloc) * 3072 + 2048 + h * 64 + dc * 8;
    bf16x8 v = *(const bf16x8*)src;
    #pragma unroll
    for (int j = 0; j < 8; ++j) lds[(dc * 8 + j) * 65 + rloc] = (unsigned short)v[j];
  }
  __syncthreads();
  const int dl = t >> 2, chunk = t & 3;
  bf16x8 o0, o1;
  #pragma unroll
  for (int j = 0; j < 8; ++j) {
    o0[j] = (short)lds[dl * 65 + chunk * 16 + j];
    o1[j] = (short)lds[dl * 65 + chunk * 16 + 8 + j];
  }
  short* dst = vT + ((size_t)bh * 64 + dl) * N_ + ntile * 64 + chunk * 16;
  *(bf16x8*)dst       = o0;
  *(bf16x8*)(dst + 8) = o1;
}

// ---------------------------------------------------------------------------
// 7) Flash attention. Round-6-proven compute per q-row, re-partitioned for
//    occupancy: 64 q-rows/block (4 waves x 16 rows), 1024 blocks = 4/CU.
//    Reg-staged double-buffered LDS; scalar f2bf pack; exact rescale.
//    XCD-grouped grid: 32 q-blocks of one bh share an XCD's L2.
// ---------------------------------------------------------------------------
__global__ __launch_bounds__(256) void attn_kernel(const short* __restrict__ qb,
                                                   const short* __restrict__ kb,
                                                   const short* __restrict__ vT,
                                                   short* __restrict__ attn_out) {
  __shared__ short Kt[2][4096];   // 8 KB per buf: [row 0..63][chunk 0..7][8]
  __shared__ short Vt[2][4096];
  const int t = threadIdx.x;
  const int lane = t & 63, w = t >> 6;
  const int c = lane & 15, g = lane >> 4;
  const int bid = blockIdx.x;               // 1024 blocks, 1D
  const int xcd = bid & 7, slot = bid >> 3; // slot 0..127
  const int bh = xcd + ((slot >> 5) << 3);  // 32 x-blocks of bh share an XCD
  const int xb = slot & 31;
  const int qrow = xb * 64 + w * 16 + c;    // this lane's q-row
  const short* kbase = kb + (size_t)bh * N_ * DH_;
  const short* vbase = vT + (size_t)bh * DH_ * N_;

  // staging map (per thread, 2 chunks per array): ch = j*256+t
  const int s_row0 = t >> 3,          s_p0 = t & 7;
  const int s_row1 = (256 + t) >> 3,  s_p1 = t & 7;   // rows 32..63
  const int s_dst0 = s_row0 * 64 + ((s_p0 ^ (s_row0 & 7)) << 3);
  const int s_dst1 = s_row1 * 64 + ((s_p1 ^ (s_row1 & 7)) << 3);

  // Q fragments held in registers for the whole kv loop; q pre-scaled 1/8
  const short* qp = qb + ((size_t)bh * N_ + qrow) * DH_;
  const bf16x8 qlo = *(const bf16x8*)(qp + g * 8);
  const bf16x8 qhi = *(const bf16x8*)(qp + 32 + g * 8);

  float M = -INFINITY, L = 0.f;
  f32x4 o[4] = {};
  bf16x8 kr0, kr1, vr0, vr1;

  // prologue: load tile 0 -> regs, write buf 0, barrier
  kr0 = *(const bf16x8*)(kbase + (size_t)s_row0 * DH_ + s_p0 * 8);
  kr1 = *(const bf16x8*)(kbase + (size_t)s_row1 * DH_ + s_p1 * 8);
  vr0 = *(const bf16x8*)(vbase + (size_t)s_row0 * N_ + s_p0 * 8);
  vr1 = *(const bf16x8*)(vbase + (size_t)s_row1 * N_ + s_p1 * 8);
  *(bf16x8*)(&Kt[0][s_dst0]) = kr0;
  *(bf16x8*)(&Kt[0][s_dst1]) = kr1;
  *(bf16x8*)(&Vt[0][s_dst0]) = vr0;
  *(bf16x8*)(&Vt[0][s_dst1]) = vr1;
  __syncthreads();

  for (int it = 0; it < 32; ++it) {
    const int cur = it & 1;
    const int pf_valid = (it + 1 < 32);
    if (pf_valid) {  // issue next-tile loads BEFORE compute (overlap)
      const int kv = (it + 1) * 64;
      kr0 = *(const bf16x8*)(kbase + (size_t)(kv + s_row0) * DH_ + s_p0 * 8);
      kr1 = *(const bf16x8*)(kbase + (size_t)(kv + s_row1) * DH_ + s_p1 * 8);
      vr0 = *(const bf16x8*)(vbase + (size_t)s_row0 * N_ + kv + s_p0 * 8);
      vr1 = *(const bf16x8*)(vbase + (size_t)s_row1 * N_ + kv + s_p1 * 8);
    }
    // --- QK^T: s[jt] lane holds S[q=qrow][j=it*64+jt*16+g*4+r] ---
    f32x4 s[4] = {};
    #pragma unroll
    for (int jt = 0; jt < 4; ++jt) {
      const int r_ = jt * 16 + c;
      const short* kt = &Kt[cur][r_ * 64];
      bf16x8 k0 = *(const bf16x8*)(kt + ((g ^ (r_ & 7)) << 3));
      bf16x8 k1 = *(const bf16x8*)(kt + (((g + 4) ^ (r_ & 7)) << 3));
      s[jt] = mfma16x16x32(k0, qlo, s[jt]);
      s[jt] = mfma16x16x32(k1, qhi, s[jt]);
    }
    // --- online softmax (exact every-tile rescale; max3-friendly chain) ---
    {
      float m0 = fmaxf(fmaxf(s[0][0], s[0][1]), s[0][2]);
      float m1 = fmaxf(fmaxf(s[0][3], s[1][0]), s[1][1]);
      float m2 = fmaxf(fmaxf(s[1][2], s[1][3]), s[2][0]);
      float m3 = fmaxf(fmaxf(s[2][1], s[2][2]), s[2][3]);
      float m4 = fmaxf(fmaxf(s[3][0], s[3][1]), s[3][2]);
      float mx = fmaxf(fmaxf(fmaxf(m0, m1), fmaxf(m2, m3)),
                       fmaxf(m4, s[3][3]));
      mx = fmaxf(mx, __shfl_xor(mx, 16));
      mx = fmaxf(mx, __shfl_xor(mx, 32));
      const float mnew = fmaxf(M, mx);
      const float corr = __expf(M - mnew);  // exp(-inf)=0 first tile
      float rs = 0.f;
      #pragma unroll
      for (int jt = 0; jt < 4; ++jt)
        #pragma unroll
        for (int r = 0; r < 4; ++r) {
          s[jt][r] = __expf(s[jt][r] - mnew);
          rs += s[jt][r];
        }
      rs += __shfl_xor(rs, 16);
      rs += __shfl_xor(rs, 32);
      L = L * corr + rs;
      M = mnew;
      #pragma unroll
      for (int dt = 0; dt < 4; ++dt) o[dt] *= corr;
    }
    // --- P pack (scalar f2bf, proven) ---
    bf16x8 pf0, pf1;
    #pragma unroll
    for (int r = 0; r < 4; ++r) {
      pf0[r]     = f2bf(s[0][r]);
      pf0[4 + r] = f2bf(s[1][r]);
      pf1[r]     = f2bf(s[2][r]);
      pf1[4 + r] = f2bf(s[3][r]);
    }
    // --- PV: A = V^T rows d, slot map j = kf*32 + (s<4 ? g*4+s : 16+g*4+s-4)
    #pragma unroll
    for (int dt = 0; dt < 4; ++dt) {
      const int d = dt * 16 + c;
      const short* vt = &Vt[cur][d * 64];
      const int dx = d & 7;
      #pragma unroll
      for (int kf = 0; kf < 2; ++kf) {
        const int e0 = kf * 32 + g * 4;
        const int e1 = e0 + 16;
        bf16x4 a0 = *(const bf16x4*)(vt + ((((e0 >> 3) ^ dx) << 3) | (e0 & 7)));
        bf16x4 a1 = *(const bf16x4*)(vt + ((((e1 >> 3) ^ dx) << 3) | (e1 & 7)));
        bf16x8 vf = __builtin_shufflevector(a0, a1, 0, 1, 2, 3, 4, 5, 6, 7);
        o[dt] = mfma16x16x32(vf, (kf == 0) ? pf0 : pf1, o[dt]);
      }
    }
    // --- write-late: store prefetched regs into the idle buffer ---
    if (pf_valid) {
      *(bf16x8*)(&Kt[cur ^ 1][s_dst0]) = kr0;
      *(bf16x8*)(&Kt[cur ^ 1][s_dst1]) = kr1;
      *(bf16x8*)(&Vt[cur ^ 1][s_dst0]) = vr0;
      *(bf16x8*)(&Vt[cur ^ 1][s_dst1]) = vr1;
    }
    __syncthreads();
  }

  const int b = bh >> 4, h = bh & 15;
  const float inv = 1.0f / L;
  short* op = attn_out + ((size_t)b * N_ + qrow) * (H_ * DH_) + h * DH_;
  #pragma unroll
  for (int dt = 0; dt < 4; ++dt) {
    bf16x4 ov;
    #pragma unroll
    for (int r = 0; r < 4; ++r) ov[r] = f2bf(o[dt][r] * inv);
    *(bf16x4*)(op + dt * 16 + g * 4) = ov;
  }
}

// ---------------------------------------------------------------------------
extern "C" void kernel_launch(void* const* d_in, const int* in_sizes, int n_in,
                              void* d_out, int out_size, void* d_ws, size_t ws_size,
                              hipStream_t stream) {
  const float* x    = (const float*)d_in[0];
  const float* Wqkv = (const float*)d_in[1];
  const float* Wout = (const float*)d_in[2];
  char* ws = (char*)d_ws;
  // workspace layout (MiB offsets)
  short* xb    = (short*)(ws);                        // 8 MiB  [4096][1024]
  short* WqkvT = (short*)(ws + ((size_t)8 << 20));    // 6 MiB  [3072][1024]
  short* WoutT = (short*)(ws + ((size_t)14 << 20));   // 2 MiB  [1024][1024]
  short* qkv   = (short*)(ws + ((size_t)16 << 20));   // 24 MiB [4096][3072]
  short* qb    = (short*)(ws + ((size_t)40 << 20));   // 8 MiB  [32][2048][64]
  short* kb    = (short*)(ws + ((size_t)48 << 20));   // 8 MiB
  short* vT    = (short*)(ws + ((size_t)56 << 20));   // 8 MiB  [32][64][2048]
  short* attn  = (short*)(ws + ((size_t)64 << 20));   // 8 MiB  [4096][1024]
  float* cs    = (float*)(ws + ((size_t)72 << 20));   // 0.5 MiB [2048][32][2]

  cs_kernel<<<dim3(256), 256, 0, stream>>>(cs);
  conv_kernel<<<dim3(2048), 256, 0, stream>>>(x, xb);                       // x -> bf16
  transw_kernel<<<dim3(48, 16), 256, 0, stream>>>(Wqkv, WqkvT, 1024, 3072); // Wqkv^T
  transw_kernel<<<dim3(16, 16), 256, 0, stream>>>(Wout, WoutT, 1024, 1024); // Wout^T
  gemm_bt_kernel<true><<<dim3(768), 256, 0, stream>>>(xb, WqkvT, (void*)qkv, 4096, 3072, 1024, 24);
  ropeqk_kernel<<<dim3(8192), 256, 0, stream>>>(qkv, cs, qb, kb);
  transv_kernel<<<dim3(32, 32), 256, 0, stream>>>(qkv, vT);
  attn_kernel<<<dim3(1024), 256, 0, stream>>>(qb, kb, vT, attn);
  gemm_bt_kernel<false><<<dim3(256), 256, 0, stream>>>(attn, WoutT, d_out, 4096, 1024, 1024, 8);
}

// Round 9
// 166.254 us; speedup vs baseline: 1.0759x; 1.0759x over previous
//
#include <hip/hip_runtime.h>
#include <hip/hip_bf16.h>
#include <stdint.h>
#include <math.h>

using bf16x8 = __attribute__((ext_vector_type(8))) short;
using bf16x4 = __attribute__((ext_vector_type(4))) short;
using f32x4  = __attribute__((ext_vector_type(4))) float;

#define DEV static __device__ __forceinline__

// SESSION LEDGER:
//  - round 5/6 bisect: BK=64 swizzled-glds GEMM => NaN. BANNED. BK=32 m97 GEMM proven.
//  - round 6/7 bisect: v_cvt_pk_bf16_f32 INLINE ASM => NaN. This round tests the
//    COMPILER path (__float22bfloat162_rn, m240-endorsed). If NaN recurs, the
//    cvt_pk instruction path is broken on this stack -> revert to scalar f2bf.
//  - round 8: attn 64-row blocks (4/CU) REGRESSED 84.6->94.3 (2x staging/LDS work,
//    VALUBusy pinned ~63% either way => VALU-issue-bound; reuse > occupancy).

DEV float bf2f(short s) {
  union { unsigned u; float f; } v; v.u = ((unsigned)(unsigned short)s) << 16; return v.f;
}
DEV short f2bf(float f) {
  union { float ff; unsigned u; } v; v.ff = f;
  unsigned r = v.u + 0x7fffu + ((v.u >> 16) & 1u);
  return (short)(r >> 16);
}
DEV unsigned packbf(float a, float b) {  // lo16 = RNE(a), hi16 = RNE(b)
  __hip_bfloat162 h = __float22bfloat162_rn(make_float2(a, b));
  union { __hip_bfloat162 h2; unsigned u; } v; v.h2 = h; return v.u;
}

DEV f32x4 mfma16x16x32(bf16x8 a, bf16x8 b, f32x4 c) {
  return __builtin_amdgcn_mfma_f32_16x16x32_bf16(a, b, c, 0, 0, 0);
}

DEV void glds16(const void* g, void* l) {
  __builtin_amdgcn_global_load_lds(
      (__attribute__((address_space(1))) void*)(uintptr_t)(g),
      (__attribute__((address_space(3))) void*)(l), 16, 0, 0);
}

#define B_   2
#define N_   2048
#define DIM_ 1024
#define H_   16
#define DH_  64
#define BH_  (B_ * H_)
#define BN_  (B_ * N_)

// ---------------------------------------------------------------------------
// 1) cos/sin table: cs[(n*32+j)*2] = cos(n * 10000^(-2j/64)), +1 = sin
// ---------------------------------------------------------------------------
__global__ void cs_kernel(float* __restrict__ cs) {
  int tid = blockIdx.x * blockDim.x + threadIdx.x;   // 65536 = 2048 * 32
  int n = tid >> 5, j = tid & 31;
  float inv = powf(10000.0f, -(float)(2 * j) / 64.0f);
  float ang = (float)n * inv;
  cs[2 * tid]     = cosf(ang);
  cs[2 * tid + 1] = sinf(ang);
}

// ---------------------------------------------------------------------------
// 2) fp32 -> bf16 elementwise (for x)
// ---------------------------------------------------------------------------
__global__ __launch_bounds__(256) void conv_kernel(const float* __restrict__ src,
                                                   short* __restrict__ dst) {
  int i = (blockIdx.x * 256 + threadIdx.x) * 8;
  float4 a = *(const float4*)(src + i);
  float4 b = *(const float4*)(src + i + 4);
  bf16x8 o;
  o[0] = f2bf(a.x); o[1] = f2bf(a.y); o[2] = f2bf(a.z); o[3] = f2bf(a.w);
  o[4] = f2bf(b.x); o[5] = f2bf(b.y); o[6] = f2bf(b.z); o[7] = f2bf(b.w);
  *(bf16x8*)(dst + i) = o;
}

// ---------------------------------------------------------------------------
// 3) transpose fp32 [R][C] -> bf16 [C][R]  (64x64 LDS tiles)
// ---------------------------------------------------------------------------
__global__ __launch_bounds__(256) void transw_kernel(const float* __restrict__ src,
                                                     short* __restrict__ dst,
                                                     int R, int C) {
  __shared__ unsigned short lds[64 * 65];
  const int t = threadIdx.x;
  const int cb = blockIdx.x * 64, rb = blockIdx.y * 64;
  #pragma unroll
  for (int pass = 0; pass < 4; ++pass) {
    int r  = pass * 16 + (t >> 4);
    int cc = (t & 15) * 4;
    float4 v = *(const float4*)(src + (size_t)(rb + r) * C + cb + cc);
    lds[(cc + 0) * 65 + r] = (unsigned short)f2bf(v.x);
    lds[(cc + 1) * 65 + r] = (unsigned short)f2bf(v.y);
    lds[(cc + 2) * 65 + r] = (unsigned short)f2bf(v.z);
    lds[(cc + 3) * 65 + r] = (unsigned short)f2bf(v.w);
  }
  __syncthreads();
  const int cl = t >> 2, chunk = t & 3;
  bf16x8 o0, o1;
  #pragma unroll
  for (int j = 0; j < 8; ++j) {
    o0[j] = (short)lds[cl * 65 + chunk * 16 + j];
    o1[j] = (short)lds[cl * 65 + chunk * 16 + 8 + j];
  }
  size_t off = (size_t)(cb + cl) * R + rb + chunk * 16;
  *(bf16x8*)(dst + off)     = o0;
  *(bf16x8*)(dst + off + 8) = o1;
}

// ---------------------------------------------------------------------------
// 4) GEMM: C[M][N] = A[M][K] (bf16, row-major) @ BT[N][K]^T (bf16)
//    Proven m97 form: 128x128 tile, BK=32, 4 waves, linear-source
//    global_load_lds. 1D grid + bijective XCD swizzle (nwg % 8 == 0).
// ---------------------------------------------------------------------------
template <bool OUTBF16>
__global__ __launch_bounds__(256) void gemm_bt_kernel(const short* __restrict__ A,
                                                      const short* __restrict__ BT,
                                                      void* __restrict__ Cout,
                                                      int M, int N, int K, int gx) {
  __shared__ short As[128 * 32];
  __shared__ short Bs[128 * 32];
  const int nwg = gridDim.x;
  const int bid = blockIdx.x;
  const int swz = (bid & 7) * (nwg >> 3) + (bid >> 3);  // bijective: nwg%8==0
  const int bx = swz % gx, by = swz / gx;
  const int t = threadIdx.x;
  const int lane = t & 63, w = t >> 6;
  const int c = lane & 15, g = lane >> 4;
  const int wm = w >> 1, wn = w & 1;
  const int mbase = by * 128, nbase = bx * 128;
  const short* Ab = A + (size_t)mbase * K;
  const short* Bb = BT + (size_t)nbase * K;
  const int sr  = t >> 2;        // staging row 0..63
  const int sc2 = (t & 3) * 8;   // staging col chunk (8 bf16 = 16 B)
  f32x4 acc[4][4] = {};
  for (int kb2 = 0; kb2 < K; kb2 += 32) {
    glds16(Ab + (size_t)sr * K + kb2 + sc2,        As + t * 8);
    glds16(Ab + (size_t)(sr + 64) * K + kb2 + sc2, As + 2048 + t * 8);
    glds16(Bb + (size_t)sr * K + kb2 + sc2,        Bs + t * 8);
    glds16(Bb + (size_t)(sr + 64) * K + kb2 + sc2, Bs + 2048 + t * 8);
    __syncthreads();
    bf16x8 af[4], bfr[4];
    #pragma unroll
    for (int mi = 0; mi < 4; ++mi)
      af[mi] = *(const bf16x8*)&As[(wm * 64 + mi * 16 + c) * 32 + g * 8];
    #pragma unroll
    for (int ni = 0; ni < 4; ++ni)
      bfr[ni] = *(const bf16x8*)&Bs[(wn * 64 + ni * 16 + c) * 32 + g * 8];
    #pragma unroll
    for (int mi = 0; mi < 4; ++mi)
      #pragma unroll
      for (int ni = 0; ni < 4; ++ni)
        acc[mi][ni] = mfma16x16x32(af[mi], bfr[ni], acc[mi][ni]);
    __syncthreads();
  }
  #pragma unroll
  for (int mi = 0; mi < 4; ++mi) {
    const int row = mbase + wm * 64 + mi * 16 + g * 4;
    #pragma unroll
    for (int ni = 0; ni < 4; ++ni) {
      const int col = nbase + wn * 64 + ni * 16 + c;
      #pragma unroll
      for (int r = 0; r < 4; ++r) {
        if constexpr (OUTBF16)
          ((short*)Cout)[(size_t)(row + r) * N + col] = f2bf(acc[mi][ni][r]);
        else
          ((float*)Cout)[(size_t)(row + r) * N + col] = acc[mi][ni][r];
      }
    }
  }
}

// ---------------------------------------------------------------------------
// 5) RoPE on q,k: qkv bf16 [4096][3072] cols 0..2047 -> qb/kb [BH][N][64] bf16
//    q additionally scaled by 0.125 (EXACT pow2, folds softmax scale)
// ---------------------------------------------------------------------------
__global__ __launch_bounds__(256) void ropeqk_kernel(const short* __restrict__ qkv,
                                                     const float* __restrict__ cs,
                                                     short* __restrict__ qb,
                                                     short* __restrict__ kb) {
  int tid = blockIdx.x * 256 + threadIdx.x;  // 2097152 threads, 4 elems each
  int e   = tid * 4;
  int bn  = e >> 11;
  int col = e & 2047;
  int i3  = col >> 10;
  int h   = (col >> 6) & 15;
  int d   = col & 63;
  int n   = bn & (N_ - 1);
  int b   = bn >> 11;
  bf16x4 v = *(const bf16x4*)(qkv + (size_t)bn * 3072 + col);
  float4 t4 = *(const float4*)(cs + ((size_t)n * 32 + (d >> 1)) * 2); // c0,s0,c1,s1
  float x0 = bf2f(v[0]), x1 = bf2f(v[1]), x2 = bf2f(v[2]), x3 = bf2f(v[3]);
  float r0 = x0 * t4.x - x1 * t4.y;
  float r1 = x0 * t4.y + x1 * t4.x;
  float r2 = x2 * t4.z - x3 * t4.w;
  float r3 = x2 * t4.w + x3 * t4.z;
  float sc = (i3 == 0) ? 0.125f : 1.0f;
  bf16x4 ov;
  ov[0] = f2bf(r0 * sc); ov[1] = f2bf(r1 * sc);
  ov[2] = f2bf(r2 * sc); ov[3] = f2bf(r3 * sc);
  short* dst = (i3 == 0) ? qb : kb;
  *(bf16x4*)(dst + (((size_t)(b * H_ + h) * N_ + n) * DH_ + d)) = ov;
}

// ---------------------------------------------------------------------------
// 6) V transpose: qkv cols 2048..3071 -> vT [BH][64][N] bf16
// ---------------------------------------------------------------------------
__global__ __launch_bounds__(256) void transv_kernel(const short* __restrict__ qkv,
                                                     short* __restrict__ vT) {
  __shared__ unsigned short lds[64 * 65];
  const int t = threadIdx.x;
  const int ntile = blockIdx.x;  // 0..31
  const int bh = blockIdx.y;     // 0..31
  const int b = bh >> 4, h = bh & 15;
  #pragma unroll
  for (int pass = 0; pass < 2; ++pass) {
    int rloc = pass * 32 + (t >> 3);
    int dc = t & 7;
    const short* src = qkv + (size_t)(b * N_ + ntile * 64 + rloc) * 3072 + 2048 + h * 64 + dc * 8;
    bf16x8 v = *(const bf16x8*)src;
    #pragma unroll
    for (int j = 0; j < 8; ++j) lds[(dc * 8 + j) * 65 + rloc] = (unsigned short)v[j];
  }
  __syncthreads();
  const int dl = t >> 2, chunk = t & 3;
  bf16x8 o0, o1;
  #pragma unroll
  for (int j = 0; j < 8; ++j) {
    o0[j] = (short)lds[dl * 65 + chunk * 16 + j];
    o1[j] = (short)lds[dl * 65 + chunk * 16 + 8 + j];
  }
  short* dst = vT + ((size_t)bh * 64 + dl) * N_ + ntile * 64 + chunk * 16;
  *(bf16x8*)dst       = o0;
  *(bf16x8*)(dst + 8) = o1;
}

// ---------------------------------------------------------------------------
// 7) Flash attention — round-6 green structure (128 q-rows/block, 4 waves x 32).
//    Changes this round: (a) P-pack via __float22bfloat162_rn (compiler packed
//    cvt, RNE-identical to scalar f2bf); (b) s_setprio around MFMA clusters.
// ---------------------------------------------------------------------------
__global__ __launch_bounds__(256) void attn_kernel(const short* __restrict__ qb,
                                                   const short* __restrict__ kb,
                                                   const short* __restrict__ vT,
                                                   short* __restrict__ attn_out) {
  __shared__ short Kt[2][4096];   // 8 KB per buf: [row 0..63][chunk 0..7][8]
  __shared__ short Vt[2][4096];
  const int t = threadIdx.x;
  const int lane = t & 63, w = t >> 6;
  const int c = lane & 15, g = lane >> 4;
  const int bid = blockIdx.x;               // 512 blocks, 1D
  const int xcd = bid & 7, slot = bid >> 3; // slot 0..63
  const int bh = xcd + ((slot >> 4) << 3);  // 16 x-blocks of bh share an XCD
  const int xb = slot & 15;
  const int qbase = xb * 128 + w * 32;
  const short* kbase = kb + (size_t)bh * N_ * DH_;
  const short* vbase = vT + (size_t)bh * DH_ * N_;

  // staging map (per thread, 2 chunks per array): ch = j*256+t
  const int s_row0 = t >> 3,          s_p0 = t & 7;
  const int s_row1 = (256 + t) >> 3,  s_p1 = t & 7;   // rows 32..63
  const int s_dst0 = s_row0 * 64 + ((s_p0 ^ (s_row0 & 7)) << 3);
  const int s_dst1 = s_row1 * 64 + ((s_p1 ^ (s_row1 & 7)) << 3);

  // Q fragments held in registers for the whole kv loop; q pre-scaled 1/8
  bf16x8 qlo[2], qhi[2];
  #pragma unroll
  for (int qf = 0; qf < 2; ++qf) {
    const short* qp = qb + ((size_t)bh * N_ + qbase + qf * 16 + c) * DH_;
    qlo[qf] = *(const bf16x8*)(qp + g * 8);
    qhi[qf] = *(const bf16x8*)(qp + 32 + g * 8);
  }

  float M[2] = {-INFINITY, -INFINITY};
  float L[2] = {0.f, 0.f};
  f32x4 o[4][2] = {};
  bf16x8 kr0, kr1, vr0, vr1;

  // prologue: load tile 0 -> regs, write buf 0, barrier
  kr0 = *(const bf16x8*)(kbase + (size_t)s_row0 * DH_ + s_p0 * 8);
  kr1 = *(const bf16x8*)(kbase + (size_t)s_row1 * DH_ + s_p1 * 8);
  vr0 = *(const bf16x8*)(vbase + (size_t)s_row0 * N_ + s_p0 * 8);
  vr1 = *(const bf16x8*)(vbase + (size_t)s_row1 * N_ + s_p1 * 8);
  *(bf16x8*)(&Kt[0][s_dst0]) = kr0;
  *(bf16x8*)(&Kt[0][s_dst1]) = kr1;
  *(bf16x8*)(&Vt[0][s_dst0]) = vr0;
  *(bf16x8*)(&Vt[0][s_dst1]) = vr1;
  __syncthreads();

  for (int it = 0; it < 32; ++it) {
    const int cur = it & 1;
    const int pf_valid = (it + 1 < 32);
    if (pf_valid) {  // issue next-tile loads BEFORE compute (overlap)
      const int kv = (it + 1) * 64;
      kr0 = *(const bf16x8*)(kbase + (size_t)(kv + s_row0) * DH_ + s_p0 * 8);
      kr1 = *(const bf16x8*)(kbase + (size_t)(kv + s_row1) * DH_ + s_p1 * 8);
      vr0 = *(const bf16x8*)(vbase + (size_t)s_row0 * N_ + kv + s_p0 * 8);
      vr1 = *(const bf16x8*)(vbase + (size_t)s_row1 * N_ + kv + s_p1 * 8);
    }
    // --- QK^T: s lane holds S[q=qf*16+c][j=it*64+jt*16+g*4+r] ---
    f32x4 s[4][2] = {};
    __builtin_amdgcn_s_setprio(1);
    #pragma unroll
    for (int jt = 0; jt < 4; ++jt) {
      const int r_ = jt * 16 + c;
      const short* kt = &Kt[cur][r_ * 64];
      bf16x8 k0 = *(const bf16x8*)(kt + ((g ^ (r_ & 7)) << 3));
      bf16x8 k1 = *(const bf16x8*)(kt + (((g + 4) ^ (r_ & 7)) << 3));
      #pragma unroll
      for (int qf = 0; qf < 2; ++qf) {
        s[jt][qf] = mfma16x16x32(k0, qlo[qf], s[jt][qf]);
        s[jt][qf] = mfma16x16x32(k1, qhi[qf], s[jt][qf]);
      }
    }
    __builtin_amdgcn_s_setprio(0);
    // --- online softmax (exact every-tile rescale; max3-friendly chain) ---
    bf16x8 pf[2][2];
    #pragma unroll
    for (int qf = 0; qf < 2; ++qf) {
      float m0 = fmaxf(fmaxf(s[0][qf][0], s[0][qf][1]), s[0][qf][2]);
      float m1 = fmaxf(fmaxf(s[0][qf][3], s[1][qf][0]), s[1][qf][1]);
      float m2 = fmaxf(fmaxf(s[1][qf][2], s[1][qf][3]), s[2][qf][0]);
      float m3 = fmaxf(fmaxf(s[2][qf][1], s[2][qf][2]), s[2][qf][3]);
      float m4 = fmaxf(fmaxf(s[3][qf][0], s[3][qf][1]), s[3][qf][2]);
      float mx = fmaxf(fmaxf(fmaxf(m0, m1), fmaxf(m2, m3)),
                       fmaxf(m4, s[3][qf][3]));
      mx = fmaxf(mx, __shfl_xor(mx, 16));
      mx = fmaxf(mx, __shfl_xor(mx, 32));
      const float mnew = fmaxf(M[qf], mx);
      const float corr = __expf(M[qf] - mnew);  // exp(-inf)=0 first tile
      float rs = 0.f;
      #pragma unroll
      for (int jt = 0; jt < 4; ++jt)
        #pragma unroll
        for (int r = 0; r < 4; ++r) {
          s[jt][qf][r] = __expf(s[jt][qf][r] - mnew);
          rs += s[jt][qf][r];
        }
      rs += __shfl_xor(rs, 16);
      rs += __shfl_xor(rs, 32);
      L[qf] = L[qf] * corr + rs;
      M[qf] = mnew;
      #pragma unroll
      for (int dt = 0; dt < 4; ++dt) o[dt][qf] *= corr;
      union { unsigned u[4]; bf16x8 v; } P0, P1;
      P0.u[0] = packbf(s[0][qf][0], s[0][qf][1]);
      P0.u[1] = packbf(s[0][qf][2], s[0][qf][3]);
      P0.u[2] = packbf(s[1][qf][0], s[1][qf][1]);
      P0.u[3] = packbf(s[1][qf][2], s[1][qf][3]);
      P1.u[0] = packbf(s[2][qf][0], s[2][qf][1]);
      P1.u[1] = packbf(s[2][qf][2], s[2][qf][3]);
      P1.u[2] = packbf(s[3][qf][0], s[3][qf][1]);
      P1.u[3] = packbf(s[3][qf][2], s[3][qf][3]);
      pf[qf][0] = P0.v;
      pf[qf][1] = P1.v;
    }
    // --- PV: A = V^T rows d, slot map j = kf*32 + (s<4 ? g*4+s : 16+g*4+s-4)
    __builtin_amdgcn_s_setprio(1);
    #pragma unroll
    for (int dt = 0; dt < 4; ++dt) {
      const int d = dt * 16 + c;
      const short* vt = &Vt[cur][d * 64];
      const int dx = d & 7;
      #pragma unroll
      for (int kf = 0; kf < 2; ++kf) {
        const int e0 = kf * 32 + g * 4;
        const int e1 = e0 + 16;
        bf16x4 a0 = *(const bf16x4*)(vt + ((((e0 >> 3) ^ dx) << 3) | (e0 & 7)));
        bf16x4 a1 = *(const bf16x4*)(vt + ((((e1 >> 3) ^ dx) << 3) | (e1 & 7)));
        bf16x8 vf = __builtin_shufflevector(a0, a1, 0, 1, 2, 3, 4, 5, 6, 7);
        o[dt][0] = mfma16x16x32(vf, pf[0][kf], o[dt][0]);
        o[dt][1] = mfma16x16x32(vf, pf[1][kf], o[dt][1]);
      }
    }
    __builtin_amdgcn_s_setprio(0);
    // --- write-late: store prefetched regs into the idle buffer ---
    if (pf_valid) {
      *(bf16x8*)(&Kt[cur ^ 1][s_dst0]) = kr0;
      *(bf16x8*)(&Kt[cur ^ 1][s_dst1]) = kr1;
      *(bf16x8*)(&Vt[cur ^ 1][s_dst0]) = vr0;
      *(bf16x8*)(&Vt[cur ^ 1][s_dst1]) = vr1;
    }
    __syncthreads();
  }

  const int b = bh >> 4, h = bh & 15;
  #pragma unroll
  for (int qf = 0; qf < 2; ++qf) {
    const float inv = 1.0f / L[qf];
    short* op = attn_out + ((size_t)b * N_ + qbase + qf * 16 + c) * (H_ * DH_) + h * DH_;
    #pragma unroll
    for (int dt = 0; dt < 4; ++dt) {
      bf16x4 ov;
      #pragma unroll
      for (int r = 0; r < 4; ++r) ov[r] = f2bf(o[dt][qf][r] * inv);
      *(bf16x4*)(op + dt * 16 + g * 4) = ov;
    }
  }
}

// ---------------------------------------------------------------------------
extern "C" void kernel_launch(void* const* d_in, const int* in_sizes, int n_in,
                              void* d_out, int out_size, void* d_ws, size_t ws_size,
                              hipStream_t stream) {
  const float* x    = (const float*)d_in[0];
  const float* Wqkv = (const float*)d_in[1];
  const float* Wout = (const float*)d_in[2];
  char* ws = (char*)d_ws;
  // workspace layout (MiB offsets)
  short* xb    = (short*)(ws);                        // 8 MiB  [4096][1024]
  short* WqkvT = (short*)(ws + ((size_t)8 << 20));    // 6 MiB  [3072][1024]
  short* WoutT = (short*)(ws + ((size_t)14 << 20));   // 2 MiB  [1024][1024]
  short* qkv   = (short*)(ws + ((size_t)16 << 20));   // 24 MiB [4096][3072]
  short* qb    = (short*)(ws + ((size_t)40 << 20));   // 8 MiB  [32][2048][64]
  short* kb    = (short*)(ws + ((size_t)48 << 20));   // 8 MiB
  short* vT    = (short*)(ws + ((size_t)56 << 20));   // 8 MiB  [32][64][2048]
  short* attn  = (short*)(ws + ((size_t)64 << 20));   // 8 MiB  [4096][1024]
  float* cs    = (float*)(ws + ((size_t)72 << 20));   // 0.5 MiB [2048][32][2]

  cs_kernel<<<dim3(256), 256, 0, stream>>>(cs);
  conv_kernel<<<dim3(2048), 256, 0, stream>>>(x, xb);                       // x -> bf16
  transw_kernel<<<dim3(48, 16), 256, 0, stream>>>(Wqkv, WqkvT, 1024, 3072); // Wqkv^T
  transw_kernel<<<dim3(16, 16), 256, 0, stream>>>(Wout, WoutT, 1024, 1024); // Wout^T
  gemm_bt_kernel<true><<<dim3(768), 256, 0, stream>>>(xb, WqkvT, (void*)qkv, 4096, 3072, 1024, 24);
  ropeqk_kernel<<<dim3(8192), 256, 0, stream>>>(qkv, cs, qb, kb);
  transv_kernel<<<dim3(32, 32), 256, 0, stream>>>(qkv, vT);
  attn_kernel<<<dim3(512), 256, 0, stream>>>(qb, kb, vT, attn);
  gemm_bt_kernel<false><<<dim3(256), 256, 0, stream>>>(attn, WoutT, d_out, 4096, 1024, 1024, 8);
}

// Round 10
// 161.010 us; speedup vs baseline: 1.1110x; 1.0326x over previous
//
#include <hip/hip_runtime.h>
#include <hip/hip_bf16.h>
#include <stdint.h>
#include <math.h>

using bf16x8 = __attribute__((ext_vector_type(8))) short;
using bf16x4 = __attribute__((ext_vector_type(4))) short;
using f32x4  = __attribute__((ext_vector_type(4))) float;

#define DEV static __device__ __forceinline__

// SESSION LEDGER:
//  - r6/7 bisect: v_cvt_pk_bf16_f32 INLINE ASM => NaN. BANNED.
//    __float22bfloat162_rn compiler path => green (r9). Use packbf.
//  - r8: attn 64-row blocks (4/CU) REGRESSED (2x staging; VALU-issue-bound;
//    reuse > occupancy). attn stays 128 q-rows/block.
//  - r4/5 BK=64 GEMM suspicion RETRACTED: never isolated (cvtpk asm present
//    in both). THIS ROUND isolates BK=64 swizzled-glds GEMM on green base.
//    If NaN => genuinely broken, permanent ban; else keep (~15 us win).

DEV float bf2f(short s) {
  union { unsigned u; float f; } v; v.u = ((unsigned)(unsigned short)s) << 16; return v.f;
}
DEV short f2bf(float f) {
  union { float ff; unsigned u; } v; v.ff = f;
  unsigned r = v.u + 0x7fffu + ((v.u >> 16) & 1u);
  return (short)(r >> 16);
}
DEV unsigned packbf(float a, float b) {  // lo16 = RNE(a), hi16 = RNE(b)
  __hip_bfloat162 h = __float22bfloat162_rn(make_float2(a, b));
  union { __hip_bfloat162 h2; unsigned u; } v; v.h2 = h; return v.u;
}

DEV f32x4 mfma16x16x32(bf16x8 a, bf16x8 b, f32x4 c) {
  return __builtin_amdgcn_mfma_f32_16x16x32_bf16(a, b, c, 0, 0, 0);
}

DEV void glds16(const void* g, void* l) {
  __builtin_amdgcn_global_load_lds(
      (__attribute__((address_space(1))) void*)(uintptr_t)(g),
      (__attribute__((address_space(3))) void*)(l), 16, 0, 0);
}

#define B_   2
#define N_   2048
#define DIM_ 1024
#define H_   16
#define DH_  64
#define BH_  (B_ * H_)
#define BN_  (B_ * N_)

// ---------------------------------------------------------------------------
// 1) cos/sin table: cs[(n*32+j)*2] = cos(n * 10000^(-2j/64)), +1 = sin
// ---------------------------------------------------------------------------
__global__ void cs_kernel(float* __restrict__ cs) {
  int tid = blockIdx.x * blockDim.x + threadIdx.x;   // 65536 = 2048 * 32
  int n = tid >> 5, j = tid & 31;
  float inv = powf(10000.0f, -(float)(2 * j) / 64.0f);
  float ang = (float)n * inv;
  cs[2 * tid]     = cosf(ang);
  cs[2 * tid + 1] = sinf(ang);
}

// ---------------------------------------------------------------------------
// 2) fp32 -> bf16 elementwise (for x)
// ---------------------------------------------------------------------------
__global__ __launch_bounds__(256) void conv_kernel(const float* __restrict__ src,
                                                   short* __restrict__ dst) {
  int i = (blockIdx.x * 256 + threadIdx.x) * 8;
  float4 a = *(const float4*)(src + i);
  float4 b = *(const float4*)(src + i + 4);
  bf16x8 o;
  o[0] = f2bf(a.x); o[1] = f2bf(a.y); o[2] = f2bf(a.z); o[3] = f2bf(a.w);
  o[4] = f2bf(b.x); o[5] = f2bf(b.y); o[6] = f2bf(b.z); o[7] = f2bf(b.w);
  *(bf16x8*)(dst + i) = o;
}

// ---------------------------------------------------------------------------
// 3) transpose fp32 [R][C] -> bf16 [C][R]  (64x64 LDS tiles)
// ---------------------------------------------------------------------------
__global__ __launch_bounds__(256) void transw_kernel(const float* __restrict__ src,
                                                     short* __restrict__ dst,
                                                     int R, int C) {
  __shared__ unsigned short lds[64 * 65];
  const int t = threadIdx.x;
  const int cb = blockIdx.x * 64, rb = blockIdx.y * 64;
  #pragma unroll
  for (int pass = 0; pass < 4; ++pass) {
    int r  = pass * 16 + (t >> 4);
    int cc = (t & 15) * 4;
    float4 v = *(const float4*)(src + (size_t)(rb + r) * C + cb + cc);
    lds[(cc + 0) * 65 + r] = (unsigned short)f2bf(v.x);
    lds[(cc + 1) * 65 + r] = (unsigned short)f2bf(v.y);
    lds[(cc + 2) * 65 + r] = (unsigned short)f2bf(v.z);
    lds[(cc + 3) * 65 + r] = (unsigned short)f2bf(v.w);
  }
  __syncthreads();
  const int cl = t >> 2, chunk = t & 3;
  bf16x8 o0, o1;
  #pragma unroll
  for (int j = 0; j < 8; ++j) {
    o0[j] = (short)lds[cl * 65 + chunk * 16 + j];
    o1[j] = (short)lds[cl * 65 + chunk * 16 + 8 + j];
  }
  size_t off = (size_t)(cb + cl) * R + rb + chunk * 16;
  *(bf16x8*)(dst + off)     = o0;
  *(bf16x8*)(dst + off + 8) = o1;
}

// ---------------------------------------------------------------------------
// 4) GEMM: C[M][N] = A[M][K] (bf16, row-major) @ BT[N][K]^T (bf16)
//    128x128 tile, BK=64, 4 waves, global_load_lds with chunk-XOR swizzled
//    SOURCE (LDS dest lane-linear; read applies same XOR — m173 pattern).
//    Accumulation order identical to two BK=32 steps => bit-identical C.
//    1D grid + bijective XCD swizzle (nwg % 8 == 0).
// ---------------------------------------------------------------------------
template <bool OUTBF16>
__global__ __launch_bounds__(256) void gemm_bt_kernel(const short* __restrict__ A,
                                                      const short* __restrict__ BT,
                                                      void* __restrict__ Cout,
                                                      int M, int N, int K, int gx) {
  __shared__ short As[128 * 64];
  __shared__ short Bs[128 * 64];
  const int nwg = gridDim.x;
  const int bid = blockIdx.x;
  const int swz = (bid & 7) * (nwg >> 3) + (bid >> 3);  // bijective: nwg%8==0
  const int bx = swz % gx, by = swz / gx;
  const int t = threadIdx.x;
  const int lane = t & 63, w = t >> 6;
  const int c = lane & 15, g = lane >> 4;
  const int wm = w >> 1, wn = w & 1;
  const int mbase = by * 128, nbase = bx * 128;
  const short* Ab = A + (size_t)mbase * K;
  const short* Bb = BT + (size_t)nbase * K;
  f32x4 acc[4][4] = {};
  for (int kb2 = 0; kb2 < K; kb2 += 64) {
    #pragma unroll
    for (int i = 0; i < 4; ++i) {
      const int idx = i * 256 + t;             // 0..1023 chunk id
      const int row = idx >> 3, p = idx & 7;
      const int gc = ((p ^ (row & 7)) << 3);   // source chunk pre-swizzle
      glds16(Ab + (size_t)row * K + kb2 + gc, As + idx * 8);
      glds16(Bb + (size_t)row * K + kb2 + gc, Bs + idx * 8);
    }
    __syncthreads();
    bf16x8 af[4][2], bfr[4][2];
    #pragma unroll
    for (int mi = 0; mi < 4; ++mi) {
      const int r = wm * 64 + mi * 16 + c;
      #pragma unroll
      for (int kk = 0; kk < 2; ++kk)
        af[mi][kk] = *(const bf16x8*)&As[r * 64 + (((kk * 4 + g) ^ (r & 7)) << 3)];
    }
    #pragma unroll
    for (int ni = 0; ni < 4; ++ni) {
      const int r = wn * 64 + ni * 16 + c;
      #pragma unroll
      for (int kk = 0; kk < 2; ++kk)
        bfr[ni][kk] = *(const bf16x8*)&Bs[r * 64 + (((kk * 4 + g) ^ (r & 7)) << 3)];
    }
    #pragma unroll
    for (int kk = 0; kk < 2; ++kk)
      #pragma unroll
      for (int mi = 0; mi < 4; ++mi)
        #pragma unroll
        for (int ni = 0; ni < 4; ++ni)
          acc[mi][ni] = mfma16x16x32(af[mi][kk], bfr[ni][kk], acc[mi][ni]);
    __syncthreads();
  }
  #pragma unroll
  for (int mi = 0; mi < 4; ++mi) {
    const int row = mbase + wm * 64 + mi * 16 + g * 4;
    #pragma unroll
    for (int ni = 0; ni < 4; ++ni) {
      const int col = nbase + wn * 64 + ni * 16 + c;
      #pragma unroll
      for (int r = 0; r < 4; ++r) {
        if constexpr (OUTBF16)
          ((short*)Cout)[(size_t)(row + r) * N + col] = f2bf(acc[mi][ni][r]);
        else
          ((float*)Cout)[(size_t)(row + r) * N + col] = acc[mi][ni][r];
      }
    }
  }
}

// ---------------------------------------------------------------------------
// 5) RoPE on q,k: qkv bf16 [4096][3072] cols 0..2047 -> qb/kb [BH][N][64] bf16
//    q additionally scaled by 0.125 (EXACT pow2, folds softmax scale)
// ---------------------------------------------------------------------------
__global__ __launch_bounds__(256) void ropeqk_kernel(const short* __restrict__ qkv,
                                                     const float* __restrict__ cs,
                                                     short* __restrict__ qb,
                                                     short* __restrict__ kb) {
  int tid = blockIdx.x * 256 + threadIdx.x;  // 2097152 threads, 4 elems each
  int e   = tid * 4;
  int bn  = e >> 11;
  int col = e & 2047;
  int i3  = col >> 10;
  int h   = (col >> 6) & 15;
  int d   = col & 63;
  int n   = bn & (N_ - 1);
  int b   = bn >> 11;
  bf16x4 v = *(const bf16x4*)(qkv + (size_t)bn * 3072 + col);
  float4 t4 = *(const float4*)(cs + ((size_t)n * 32 + (d >> 1)) * 2); // c0,s0,c1,s1
  float x0 = bf2f(v[0]), x1 = bf2f(v[1]), x2 = bf2f(v[2]), x3 = bf2f(v[3]);
  float r0 = x0 * t4.x - x1 * t4.y;
  float r1 = x0 * t4.y + x1 * t4.x;
  float r2 = x2 * t4.z - x3 * t4.w;
  float r3 = x2 * t4.w + x3 * t4.z;
  float sc = (i3 == 0) ? 0.125f : 1.0f;
  bf16x4 ov;
  ov[0] = f2bf(r0 * sc); ov[1] = f2bf(r1 * sc);
  ov[2] = f2bf(r2 * sc); ov[3] = f2bf(r3 * sc);
  short* dst = (i3 == 0) ? qb : kb;
  *(bf16x4*)(dst + (((size_t)(b * H_ + h) * N_ + n) * DH_ + d)) = ov;
}

// ---------------------------------------------------------------------------
// 6) V transpose: qkv cols 2048..3071 -> vT [BH][64][N] bf16
// ---------------------------------------------------------------------------
__global__ __launch_bounds__(256) void transv_kernel(const short* __restrict__ qkv,
                                                     short* __restrict__ vT) {
  __shared__ unsigned short lds[64 * 65];
  const int t = threadIdx.x;
  const int ntile = blockIdx.x;  // 0..31
  const int bh = blockIdx.y;     // 0..31
  const int b = bh >> 4, h = bh & 15;
  #pragma unroll
  for (int pass = 0; pass < 2; ++pass) {
    int rloc = pass * 32 + (t >> 3);
    int dc = t & 7;
    const short* src = qkv + (size_t)(b * N_ + ntile * 64 + rloc) * 3072 + 2048 + h * 64 + dc * 8;
    bf16x8 v = *(const bf16x8*)src;
    #pragma unroll
    for (int j = 0; j < 8; ++j) lds[(dc * 8 + j) * 65 + rloc] = (unsigned short)v[j];
  }
  __syncthreads();
  const int dl = t >> 2, chunk = t & 3;
  bf16x8 o0, o1;
  #pragma unroll
  for (int j = 0; j < 8; ++j) {
    o0[j] = (short)lds[dl * 65 + chunk * 16 + j];
    o1[j] = (short)lds[dl * 65 + chunk * 16 + 8 + j];
  }
  short* dst = vT + ((size_t)bh * 64 + dl) * N_ + ntile * 64 + chunk * 16;
  *(bf16x8*)dst       = o0;
  *(bf16x8*)(dst + 8) = o1;
}

// ---------------------------------------------------------------------------
// 7) Flash attention — round-9 GREEN form, UNCHANGED.
//    128 q-rows/block (4 waves x 32), reg-staged dbuf LDS, packbf P-pack,
//    setprio around MFMA clusters, XCD-grouped 1D grid.
// ---------------------------------------------------------------------------
__global__ __launch_bounds__(256) void attn_kernel(const short* __restrict__ qb,
                                                   const short* __restrict__ kb,
                                                   const short* __restrict__ vT,
                                                   short* __restrict__ attn_out) {
  __shared__ short Kt[2][4096];   // 8 KB per buf: [row 0..63][chunk 0..7][8]
  __shared__ short Vt[2][4096];
  const int t = threadIdx.x;
  const int lane = t & 63, w = t >> 6;
  const int c = lane & 15, g = lane >> 4;
  const int bid = blockIdx.x;               // 512 blocks, 1D
  const int xcd = bid & 7, slot = bid >> 3; // slot 0..63
  const int bh = xcd + ((slot >> 4) << 3);  // 16 x-blocks of bh share an XCD
  const int xb = slot & 15;
  const int qbase = xb * 128 + w * 32;
  const short* kbase = kb + (size_t)bh * N_ * DH_;
  const short* vbase = vT + (size_t)bh * DH_ * N_;

  // staging map (per thread, 2 chunks per array): ch = j*256+t
  const int s_row0 = t >> 3,          s_p0 = t & 7;
  const int s_row1 = (256 + t) >> 3,  s_p1 = t & 7;   // rows 32..63
  const int s_dst0 = s_row0 * 64 + ((s_p0 ^ (s_row0 & 7)) << 3);
  const int s_dst1 = s_row1 * 64 + ((s_p1 ^ (s_row1 & 7)) << 3);

  // Q fragments held in registers for the whole kv loop; q pre-scaled 1/8
  bf16x8 qlo[2], qhi[2];
  #pragma unroll
  for (int qf = 0; qf < 2; ++qf) {
    const short* qp = qb + ((size_t)bh * N_ + qbase + qf * 16 + c) * DH_;
    qlo[qf] = *(const bf16x8*)(qp + g * 8);
    qhi[qf] = *(const bf16x8*)(qp + 32 + g * 8);
  }

  float M[2] = {-INFINITY, -INFINITY};
  float L[2] = {0.f, 0.f};
  f32x4 o[4][2] = {};
  bf16x8 kr0, kr1, vr0, vr1;

  // prologue: load tile 0 -> regs, write buf 0, barrier
  kr0 = *(const bf16x8*)(kbase + (size_t)s_row0 * DH_ + s_p0 * 8);
  kr1 = *(const bf16x8*)(kbase + (size_t)s_row1 * DH_ + s_p1 * 8);
  vr0 = *(const bf16x8*)(vbase + (size_t)s_row0 * N_ + s_p0 * 8);
  vr1 = *(const bf16x8*)(vbase + (size_t)s_row1 * N_ + s_p1 * 8);
  *(bf16x8*)(&Kt[0][s_dst0]) = kr0;
  *(bf16x8*)(&Kt[0][s_dst1]) = kr1;
  *(bf16x8*)(&Vt[0][s_dst0]) = vr0;
  *(bf16x8*)(&Vt[0][s_dst1]) = vr1;
  __syncthreads();

  for (int it = 0; it < 32; ++it) {
    const int cur = it & 1;
    const int pf_valid = (it + 1 < 32);
    if (pf_valid) {  // issue next-tile loads BEFORE compute (overlap)
      const int kv = (it + 1) * 64;
      kr0 = *(const bf16x8*)(kbase + (size_t)(kv + s_row0) * DH_ + s_p0 * 8);
      kr1 = *(const bf16x8*)(kbase + (size_t)(kv + s_row1) * DH_ + s_p1 * 8);
      vr0 = *(const bf16x8*)(vbase + (size_t)s_row0 * N_ + kv + s_p0 * 8);
      vr1 = *(const bf16x8*)(vbase + (size_t)s_row1 * N_ + kv + s_p1 * 8);
    }
    // --- QK^T: s lane holds S[q=qf*16+c][j=it*64+jt*16+g*4+r] ---
    f32x4 s[4][2] = {};
    __builtin_amdgcn_s_setprio(1);
    #pragma unroll
    for (int jt = 0; jt < 4; ++jt) {
      const int r_ = jt * 16 + c;
      const short* kt = &Kt[cur][r_ * 64];
      bf16x8 k0 = *(const bf16x8*)(kt + ((g ^ (r_ & 7)) << 3));
      bf16x8 k1 = *(const bf16x8*)(kt + (((g + 4) ^ (r_ & 7)) << 3));
      #pragma unroll
      for (int qf = 0; qf < 2; ++qf) {
        s[jt][qf] = mfma16x16x32(k0, qlo[qf], s[jt][qf]);
        s[jt][qf] = mfma16x16x32(k1, qhi[qf], s[jt][qf]);
      }
    }
    __builtin_amdgcn_s_setprio(0);
    // --- online softmax (exact every-tile rescale; max3-friendly chain) ---
    bf16x8 pf[2][2];
    #pragma unroll
    for (int qf = 0; qf < 2; ++qf) {
      float m0 = fmaxf(fmaxf(s[0][qf][0], s[0][qf][1]), s[0][qf][2]);
      float m1 = fmaxf(fmaxf(s[0][qf][3], s[1][qf][0]), s[1][qf][1]);
      float m2 = fmaxf(fmaxf(s[1][qf][2], s[1][qf][3]), s[2][qf][0]);
      float m3 = fmaxf(fmaxf(s[2][qf][1], s[2][qf][2]), s[2][qf][3]);
      float m4 = fmaxf(fmaxf(s[3][qf][0], s[3][qf][1]), s[3][qf][2]);
      float mx = fmaxf(fmaxf(fmaxf(m0, m1), fmaxf(m2, m3)),
                       fmaxf(m4, s[3][qf][3]));
      mx = fmaxf(mx, __shfl_xor(mx, 16));
      mx = fmaxf(mx, __shfl_xor(mx, 32));
      const float mnew = fmaxf(M[qf], mx);
      const float corr = __expf(M[qf] - mnew);  // exp(-inf)=0 first tile
      float rs = 0.f;
      #pragma unroll
      for (int jt = 0; jt < 4; ++jt)
        #pragma unroll
        for (int r = 0; r < 4; ++r) {
          s[jt][qf][r] = __expf(s[jt][qf][r] - mnew);
          rs += s[jt][qf][r];
        }
      rs += __shfl_xor(rs, 16);
      rs += __shfl_xor(rs, 32);
      L[qf] = L[qf] * corr + rs;
      M[qf] = mnew;
      #pragma unroll
      for (int dt = 0; dt < 4; ++dt) o[dt][qf] *= corr;
      union { unsigned u[4]; bf16x8 v; } P0, P1;
      P0.u[0] = packbf(s[0][qf][0], s[0][qf][1]);
      P0.u[1] = packbf(s[0][qf][2], s[0][qf][3]);
      P0.u[2] = packbf(s[1][qf][0], s[1][qf][1]);
      P0.u[3] = packbf(s[1][qf][2], s[1][qf][3]);
      P1.u[0] = packbf(s[2][qf][0], s[2][qf][1]);
      P1.u[1] = packbf(s[2][qf][2], s[2][qf][3]);
      P1.u[2] = packbf(s[3][qf][0], s[3][qf][1]);
      P1.u[3] = packbf(s[3][qf][2], s[3][qf][3]);
      pf[qf][0] = P0.v;
      pf[qf][1] = P1.v;
    }
    // --- PV: A = V^T rows d, slot map j = kf*32 + (s<4 ? g*4+s : 16+g*4+s-4)
    __builtin_amdgcn_s_setprio(1);
    #pragma unroll
    for (int dt = 0; dt < 4; ++dt) {
      const int d = dt * 16 + c;
      const short* vt = &Vt[cur][d * 64];
      const int dx = d & 7;
      #pragma unroll
      for (int kf = 0; kf < 2; ++kf) {
        const int e0 = kf * 32 + g * 4;
        const int e1 = e0 + 16;
        bf16x4 a0 = *(const bf16x4*)(vt + ((((e0 >> 3) ^ dx) << 3) | (e0 & 7)));
        bf16x4 a1 = *(const bf16x4*)(vt + ((((e1 >> 3) ^ dx) << 3) | (e1 & 7)));
        bf16x8 vf = __builtin_shufflevector(a0, a1, 0, 1, 2, 3, 4, 5, 6, 7);
        o[dt][0] = mfma16x16x32(vf, pf[0][kf], o[dt][0]);
        o[dt][1] = mfma16x16x32(vf, pf[1][kf], o[dt][1]);
      }
    }
    __builtin_amdgcn_s_setprio(0);
    // --- write-late: store prefetched regs into the idle buffer ---
    if (pf_valid) {
      *(bf16x8*)(&Kt[cur ^ 1][s_dst0]) = kr0;
      *(bf16x8*)(&Kt[cur ^ 1][s_dst1]) = kr1;
      *(bf16x8*)(&Vt[cur ^ 1][s_dst0]) = vr0;
      *(bf16x8*)(&Vt[cur ^ 1][s_dst1]) = vr1;
    }
    __syncthreads();
  }

  const int b = bh >> 4, h = bh & 15;
  #pragma unroll
  for (int qf = 0; qf < 2; ++qf) {
    const float inv = 1.0f / L[qf];
    short* op = attn_out + ((size_t)b * N_ + qbase + qf * 16 + c) * (H_ * DH_) + h * DH_;
    #pragma unroll
    for (int dt = 0; dt < 4; ++dt) {
      bf16x4 ov;
      #pragma unroll
      for (int r = 0; r < 4; ++r) ov[r] = f2bf(o[dt][qf][r] * inv);
      *(bf16x4*)(op + dt * 16 + g * 4) = ov;
    }
  }
}

// ---------------------------------------------------------------------------
extern "C" void kernel_launch(void* const* d_in, const int* in_sizes, int n_in,
                              void* d_out, int out_size, void* d_ws, size_t ws_size,
                              hipStream_t stream) {
  const float* x    = (const float*)d_in[0];
  const float* Wqkv = (const float*)d_in[1];
  const float* Wout = (const float*)d_in[2];
  char* ws = (char*)d_ws;
  // workspace layout (MiB offsets)
  short* xb    = (short*)(ws);                        // 8 MiB  [4096][1024]
  short* WqkvT = (short*)(ws + ((size_t)8 << 20));    // 6 MiB  [3072][1024]
  short* WoutT = (short*)(ws + ((size_t)14 << 20));   // 2 MiB  [1024][1024]
  short* qkv   = (short*)(ws + ((size_t)16 << 20));   // 24 MiB [4096][3072]
  short* qb    = (short*)(ws + ((size_t)40 << 20));   // 8 MiB  [32][2048][64]
  short* kb    = (short*)(ws + ((size_t)48 << 20));   // 8 MiB
  short* vT    = (short*)(ws + ((size_t)56 << 20));   // 8 MiB  [32][64][2048]
  short* attn  = (short*)(ws + ((size_t)64 << 20));   // 8 MiB  [4096][1024]
  float* cs    = (float*)(ws + ((size_t)72 << 20));   // 0.5 MiB [2048][32][2]

  cs_kernel<<<dim3(256), 256, 0, stream>>>(cs);
  conv_kernel<<<dim3(2048), 256, 0, stream>>>(x, xb);                       // x -> bf16
  transw_kernel<<<dim3(48, 16), 256, 0, stream>>>(Wqkv, WqkvT, 1024, 3072); // Wqkv^T
  transw_kernel<<<dim3(16, 16), 256, 0, stream>>>(Wout, WoutT, 1024, 1024); // Wout^T
  gemm_bt_kernel<true><<<dim3(768), 256, 0, stream>>>(xb, WqkvT, (void*)qkv, 4096, 3072, 1024, 24);
  ropeqk_kernel<<<dim3(8192), 256, 0, stream>>>(qkv, cs, qb, kb);
  transv_kernel<<<dim3(32, 32), 256, 0, stream>>>(qkv, vT);
  attn_kernel<<<dim3(512), 256, 0, stream>>>(qb, kb, vT, attn);
  gemm_bt_kernel<false><<<dim3(256), 256, 0, stream>>>(attn, WoutT, d_out, 4096, 1024, 1024, 8);
}